// Round 2
// baseline (16300.473 us; speedup 1.0000x reference)
//
#include <hip/hip_runtime.h>
#include <math.h>

// ---------------- constants ----------------
#define Bc   32
#define Nc   379
#define Hc   512
#define NHc  8
#define Pc   3
#define HDc  64          // H/NH
#define NNc  (Nc*Nc)     // 143641
#define CB   8           // batch chunk
#define NCHUNK 4
static const size_t NH_f  = (size_t)Nc*Hc;           // 194,048
static const size_t BNH   = (size_t)Bc*Nc*Hc;        // 6,207,488
#define ROWS_BN   12128   // B*N
#define ROWS_CHUNK 3032   // CB*N  (== ROWS_BN/4)
#define ROWS_WG    9096   // CB*P*N
static const size_t CHUNK_NH = (size_t)CB*Nc*Hc;     // 1,552,384
static const size_t PEC_SZ   = (size_t)ROWS_WG*Hc;   // 4,657,152
static const size_t QKVC_SZ  = (size_t)CB*Nc*3*Hc;   // 4,657,152
static const size_t HIDC_SZ  = (size_t)ROWS_CHUNK*4*Hc; // 6,209,536

__device__ inline float gelu_f(float x) {
    return 0.5f * x * (1.0f + erff(x * 0.7071067811865476f));
}

// block reductions (blockDim == 256)
__device__ inline float blk_sum(float v, float* sh) {
#pragma unroll
    for (int off = 32; off; off >>= 1) v += __shfl_xor(v, off, 64);
    int w = threadIdx.x >> 6;
    __syncthreads();
    if ((threadIdx.x & 63) == 0) sh[w] = v;
    __syncthreads();
    float t = sh[0] + sh[1] + sh[2] + sh[3];
    return t;
}
__device__ inline float blk_max(float v, float* sh) {
#pragma unroll
    for (int off = 32; off; off >>= 1) v = fmaxf(v, __shfl_xor(v, off, 64));
    int w = threadIdx.x >> 6;
    __syncthreads();
    if ((threadIdx.x & 63) == 0) sh[w] = v;
    __syncthreads();
    float t = fmaxf(fmaxf(sh[0], sh[1]), fmaxf(sh[2], sh[3]));
    return t;
}

// ---------------- generic tiled SGEMM ----------------
// C(M,N) = A(M,K) @ B(K,N), row-major. Epilogues:
// 0: none; 1: +bias; 2: gelu(+bias); 3: gelu(+bias + addsrc P-broadcast); 4: *rowscale[row/rs_div] + bias
template<int EPI>
__global__ __launch_bounds__(256) void gemm_k(
    const float* __restrict__ A, const float* __restrict__ B, float* __restrict__ C,
    int M, int N, int K,
    const float* __restrict__ bias,
    const float* __restrict__ rowscale, int rs_div,
    const float* __restrict__ addsrc, int addP, int addN)
{
    __shared__ float As[16][65];
    __shared__ float Bs[16][65];
    int tid = threadIdx.x;
    int tx = tid & 15, ty = tid >> 4;
    int m0 = blockIdx.y * 64, n0 = blockIdx.x * 64;
    float acc[4][4] = {};
    for (int k0 = 0; k0 < K; k0 += 16) {
#pragma unroll
        for (int i = 0; i < 4; i++) {
            int idx = tid + i * 256;
            int m = idx >> 4, kk = idx & 15;
            int gm = m0 + m, gk = k0 + kk;
            float v = 0.f;
            if (gm < M && gk < K) v = A[(size_t)gm * K + gk];
            As[kk][m] = v;
        }
#pragma unroll
        for (int i = 0; i < 4; i++) {
            int idx = tid + i * 256;
            int kk = idx >> 6, n = idx & 63;
            int gk = k0 + kk, gn = n0 + n;
            float v = 0.f;
            if (gk < K && gn < N) v = B[(size_t)gk * N + gn];
            Bs[kk][n] = v;
        }
        __syncthreads();
#pragma unroll
        for (int kk = 0; kk < 16; kk++) {
            float a[4], b[4];
#pragma unroll
            for (int i = 0; i < 4; i++) a[i] = As[kk][ty + 16 * i];
#pragma unroll
            for (int j = 0; j < 4; j++) b[j] = Bs[kk][tx + 16 * j];
#pragma unroll
            for (int i = 0; i < 4; i++)
#pragma unroll
                for (int j = 0; j < 4; j++) acc[i][j] += a[i] * b[j];
        }
        __syncthreads();
    }
#pragma unroll
    for (int i = 0; i < 4; i++) {
        int gm = m0 + ty + 16 * i;
        if (gm >= M) continue;
#pragma unroll
        for (int j = 0; j < 4; j++) {
            int gn = n0 + tx + 16 * j;
            if (gn >= N) continue;
            float v = acc[i][j];
            if (EPI == 1 || EPI == 2 || EPI == 3) v += bias[gn];
            if (EPI == 4) v = v * rowscale[gm / rs_div] + bias[gn];
            if (EPI == 3) {
                int addrow = (gm / (addP * addN)) * addN + (gm % addN);
                v += addsrc[(size_t)addrow * N + gn];
            }
            if (EPI == 2 || EPI == 3) v = gelu_f(v);
            C[(size_t)gm * N + gn] = v;
        }
    }
}

template<int EPI>
static void launch_gemm(const float* A, const float* B, float* C, int M, int N, int K,
                        const float* bias, const float* rowscale, int rs_div,
                        const float* addsrc, int addP, int addN, hipStream_t st) {
    dim3 grid((N + 63) / 64, (M + 63) / 64);
    gemm_k<EPI><<<grid, 256, 0, st>>>(A, B, C, M, N, K, bias, rowscale, rs_div, addsrc, addP, addN);
}

// ---------------- LayerNorm (rows of 512) ----------------
__global__ __launch_bounds__(256) void ln_k(const float* __restrict__ x,
                                            const float* __restrict__ g,
                                            const float* __restrict__ b,
                                            float* __restrict__ z) {
    __shared__ float sh[4];
    int r = blockIdx.x, t = threadIdx.x;
    const float* xr = x + (size_t)r * Hc;
    float v0 = xr[t], v1 = xr[t + 256];
    float sum = blk_sum(v0 + v1, sh);
    float sq  = blk_sum(v0 * v0 + v1 * v1, sh);
    float mean = sum * (1.f / Hc);
    float var  = sq * (1.f / Hc) - mean * mean;
    float inv  = rsqrtf(var + 1e-5f);
    float* zr = z + (size_t)r * Hc;
    zr[t]       = (v0 - mean) * inv * g[t]       + b[t];
    zr[t + 256] = (v1 - mean) * inv * g[t + 256] + b[t + 256];
}

// ---------------- weight-gen stats over priors/conn ----------------
__global__ __launch_bounds__(256) void wg_stats_k(const float* __restrict__ pri,
                                                  const float* __restrict__ conn,
                                                  float* __restrict__ mass, float* __restrict__ dot,
                                                  float* __restrict__ nrmp, float* __restrict__ nrmc) {
    __shared__ float sh[4];
    int bp = blockIdx.x;
    int b = bp >> 2, r = bp & 3;   // P+1 == 4
    const float* c = conn + (size_t)b * NNc;
    if (r < Pc) {
        const float* p = pri + (size_t)(b * Pc + r) * NNc;
        float sa = 0, sq = 0, sd = 0;
        for (int i = threadIdx.x; i < NNc; i += blockDim.x) {
            float pv = p[i], cv = c[i];
            sa += fabsf(pv); sq += pv * pv; sd += pv * cv;
        }
        sa = blk_sum(sa, sh);
        sq = blk_sum(sq, sh);
        sd = blk_sum(sd, sh);
        if (threadIdx.x == 0) { mass[b * Pc + r] = sa; nrmp[b * Pc + r] = sqrtf(sq); dot[b * Pc + r] = sd; }
    } else {
        float sq = 0;
        for (int i = threadIdx.x; i < NNc; i += blockDim.x) { float cv = c[i]; sq += cv * cv; }
        sq = blk_sum(sq, sh);
        if (threadIdx.x == 0) nrmc[b] = sqrtf(sq);
    }
}

// softmax over P of cosine sims, plus inverse mass
__global__ void wg_sw_k(const float* mass, const float* dot, const float* nrmp, const float* nrmc,
                        float* sw, float* invm) {
    int b = threadIdx.x;
    if (b >= Bc) return;
    float nc = fmaxf(nrmc[b], 1e-12f);
    float s[Pc];
    for (int p = 0; p < Pc; p++) s[p] = dot[b * Pc + p] / (nc * fmaxf(nrmp[b * Pc + p], 1e-12f));
    float m = fmaxf(s[0], fmaxf(s[1], s[2]));
    float e[Pc], sum = 0;
    for (int p = 0; p < Pc; p++) { e[p] = expf(s[p] - m); sum += e[p]; }
    for (int p = 0; p < Pc; p++) {
        sw[b * Pc + p] = e[p] / sum;
        invm[b * Pc + p] = 1.f / mass[b * Pc + p];
    }
}

// fused_nh chunk: FNp[idx] = sum_p swp[b'*3+p] * PEc[b'*3*NH + p*NH + within], idx over CB*N*H
__global__ void fused_nh_k(const float* __restrict__ PEc, const float* __restrict__ swp,
                           float* __restrict__ FNp, size_t count) {
    size_t idx = (size_t)blockIdx.x * blockDim.x + threadIdx.x;
    if (idx >= count) return;
    int bl = (int)(idx / NH_f);
    size_t within = idx % NH_f;
    const float* sw = swp + bl * Pc;
    size_t base = (size_t)bl * Pc * NH_f + within;
    FNp[idx] = sw[0] * PEc[base] + sw[1] * PEc[base + NH_f] + sw[2] * PEc[base + 2 * NH_f];
}

// tokens[bp,h] = mean_n F2[bp,n,h]  (chunk: grid = CB*P)
__global__ __launch_bounds__(512) void tokens_k(const float* __restrict__ F2, float* __restrict__ TOK) {
    int bp = blockIdx.x, h = threadIdx.x;
    const float* base = F2 + (size_t)bp * NH_f + h;
    float s = 0;
    for (int n = 0; n < Nc; n++) s += base[(size_t)n * Hc];
    TOK[(size_t)bp * Hc + h] = s * (1.0f / (float)Nc);
}

// tiny MHA over P=3 tokens -> aw_ (output) and msum
__global__ __launch_bounds__(64) void wg_attn_k(const float* __restrict__ QW,
                                                float* __restrict__ aw_out, float* __restrict__ msum) {
    int b = blockIdx.x, lane = threadIdx.x;
    float s[4][Pc][Pc];
    for (int h = 0; h < 4; h++)
        for (int i = 0; i < Pc; i++)
            for (int j = 0; j < Pc; j++) {
                const float* q = QW + (size_t)(b * Pc + i) * 1536 + h * 128;
                const float* k = QW + (size_t)(b * Pc + j) * 1536 + 512 + h * 128;
                float p = q[lane] * k[lane] + q[lane + 64] * k[lane + 64];
#pragma unroll
                for (int off = 32; off; off >>= 1) p += __shfl_xor(p, off, 64);
                s[h][i][j] = p * 0.08838834764831845f;  // 1/sqrt(128)
            }
    float aw[Pc] = {0, 0, 0};
    for (int h = 0; h < 4; h++)
        for (int i = 0; i < Pc; i++) {
            float m = fmaxf(s[h][i][0], fmaxf(s[h][i][1], s[h][i][2]));
            float e0 = expf(s[h][i][0] - m), e1 = expf(s[h][i][1] - m), e2 = expf(s[h][i][2] - m);
            float inv = 1.f / (e0 + e1 + e2);
            aw[0] += e0 * inv; aw[1] += e1 * inv; aw[2] += e2 * inv;
        }
    for (int j = 0; j < Pc; j++) aw[j] *= (1.f / 12.f);
    float m2 = fmaxf(aw[0], fmaxf(aw[1], aw[2]));
    float e0 = expf((aw[0] - m2) * 100.f), e1 = expf((aw[1] - m2) * 100.f), e2 = expf((aw[2] - m2) * 100.f);
    float inv = 1.f / (e0 + e1 + e2);
    if (lane == 0) {
        aw_out[b * Pc + 0] = e0 * inv;
        aw_out[b * Pc + 1] = e1 * inv;
        aw_out[b * Pc + 2] = e2 * inv;
        msum[b] = (e0 + e1 + e2) * inv;   // == 1 analytically, kept faithful
    }
}

// fused attention row + on-the-fly prior mask: block per (i, h, b_local); b = b0 + b_local
__global__ __launch_bounds__(256) void attn_k(const float* __restrict__ QKVc,
                                              const float* __restrict__ conn,
                                              const float* __restrict__ msum,
                                              const float* __restrict__ alpha,
                                              int b0,
                                              float* __restrict__ ctx) {
    __shared__ float qs[HDc];
    __shared__ float sc[384];
    __shared__ float sh[4];
    __shared__ float pv[4][HDc];
    int i = blockIdx.x, h = blockIdx.y, bl = blockIdx.z;
    int b = b0 + bl;
    int t = threadIdx.x;
    const float* qr = QKVc + ((size_t)bl * Nc + i) * (3 * Hc) + h * HDc;
    if (t < HDc) qs[t] = qr[t];
    __syncthreads();
    const float* Kbase = QKVc + (size_t)bl * Nc * (3 * Hc) + Hc + h * HDc;
    const float* Crow  = conn + ((size_t)b * Nc + i) * Nc;
    float a2 = 0.5f * alpha[0];
    float mterm = a2 * msum[b];
    for (int j = t; j < Nc; j += 256) {
        const float* kr = Kbase + (size_t)j * (3 * Hc);
        float d = 0;
        for (int u = 0; u < HDc; u++) d += qs[u] * kr[u];
        float mask = tanhf(mterm + (1.f - a2) * Crow[j]);
        sc[j] = d * 0.125f * (1.f + mask);
    }
    __syncthreads();
    float m = -3.4e38f;
    for (int j = t; j < Nc; j += 256) m = fmaxf(m, sc[j]);
    m = blk_max(m, sh);
    float sum = 0;
    for (int j = t; j < Nc; j += 256) { float e = expf(sc[j] - m); sc[j] = e; sum += e; }
    sum = blk_sum(sum, sh);
    __syncthreads();
    float inv = 1.f / sum;
    int d = t & 63, part = t >> 6;
    const float* Vbase = QKVc + (size_t)bl * Nc * (3 * Hc) + 2 * Hc + h * HDc;
    float acc = 0;
    for (int j = part; j < Nc; j += 4) acc += sc[j] * Vbase[(size_t)j * (3 * Hc) + d];
    pv[part][d] = acc;
    __syncthreads();
    if (t < HDc) {
        float v = pv[0][t] + pv[1][t] + pv[2][t] + pv[3][t];
        ctx[((size_t)b * Nc + i) * Hc + h * HDc + t] = v * inv;
    }
}

// attn_out = x + ctx + fn (in-place into ctx buffer)
__global__ void add3_k(const float* __restrict__ x, float* __restrict__ ctx,
                       const float* __restrict__ fn, size_t count) {
    size_t idx = (size_t)blockIdx.x * blockDim.x + threadIdx.x;
    if (idx >= count) return;
    ctx[idx] = x[idx] + ctx[idx] + fn[idx];
}

// stream 0: x_new = attn_out + ffn; proj0 = w*ffn + (1-w)*x_new
__global__ void final_k(const float* __restrict__ AO, const float* __restrict__ FF,
                        const float* __restrict__ dw,
                        float* __restrict__ xout, float* __restrict__ proj, size_t count) {
    size_t idx = (size_t)blockIdx.x * blockDim.x + threadIdx.x;
    if (idx >= count) return;
    float w = dw[0];
    float ff = FF[idx];
    float xn = AO[idx] + ff;
    xout[idx] = xn;
    proj[idx] = w * ff + (1.f - w) * xn;
}

// stream 1 fused: x_new + proj_SC + symmetric-KL row reduction vs PROJ0
__global__ __launch_bounds__(256) void final_kl_k(const float* __restrict__ AO,
                                                  const float* __restrict__ FF,
                                                  const float* __restrict__ dw,
                                                  const float* __restrict__ PF,
                                                  float* __restrict__ xout,
                                                  float* __restrict__ acc) {
    __shared__ float sh[4];
    int r = blockIdx.x, t = threadIdx.x;
    size_t base = (size_t)r * Hc;
    float w = dw[1];
    float ff0 = FF[base + t], ff1 = FF[base + t + 256];
    float ao0 = AO[base + t], ao1 = AO[base + t + 256];
    float xn0 = ao0 + ff0, xn1 = ao1 + ff1;
    xout[base + t] = xn0;
    xout[base + t + 256] = xn1;
    float s0 = w * ff0 + (1.f - w) * xn0;
    float s1 = w * ff1 + (1.f - w) * xn1;
    float f0 = PF[base + t], f1 = PF[base + t + 256];
    float mf = blk_max(fmaxf(f0, f1), sh);
    float ms = blk_max(fmaxf(s0, s1), sh);
    float ef = expf(f0 - mf) + expf(f1 - mf);
    float es = expf(s0 - ms) + expf(s1 - ms);
    float sf = blk_sum(ef, sh);
    float ss = blk_sum(es, sh);
    float lsef = mf + logf(sf), lses = ms + logf(ss);
    float lf0 = f0 - lsef, lf1 = f1 - lsef, ls0 = s0 - lses, ls1 = s1 - lses;
    float tsum = expf(ls0) * (ls0 - lf0) + expf(ls1) * (ls1 - lf1)
               + expf(lf0) * (lf0 - ls0) + expf(lf1) * (lf1 - ls1);
    tsum = blk_sum(tsum, sh);
    if (t == 0) atomicAdd(acc, tsum);
}

__global__ void kl_final_k(const float* __restrict__ acc, float* __restrict__ out) {
    out[0] = 0.5f * acc[0] * (1.0f / (float)ROWS_BN);
}

// ---------------- launch ----------------
extern "C" void kernel_launch(void* const* d_in, const int* in_sizes, int n_in,
                              void* d_out, int out_size, void* d_ws, size_t ws_size,
                              hipStream_t stream) {
    (void)in_sizes; (void)n_in; (void)out_size; (void)ws_size;
    const float* x[2]    = {(const float*)d_in[0], (const float*)d_in[1]};
    const float* pri[2]  = {(const float*)d_in[2], (const float*)d_in[3]};
    const float* conn[2] = {(const float*)d_in[4], (const float*)d_in[5]};
    const float* dw      = (const float*)d_in[6];
    const float* wqkv[2] = {(const float*)d_in[7], (const float*)d_in[8]};
    const float* ln_g    = (const float*)d_in[9];
    const float* ln_b    = (const float*)d_in[10];
    const float* ffn_w1  = (const float*)d_in[11];
    const float* ffn_b1  = (const float*)d_in[12];
    const float* ffn_w2  = (const float*)d_in[13];
    const float* ffn_b2  = (const float*)d_in[14];
    const float* pw      = (const float*)d_in[15];
    const float* pb      = (const float*)d_in[16];
    const float* f1w     = (const float*)d_in[17];
    const float* f1b     = (const float*)d_in[18];
    const float* f2w     = (const float*)d_in[19];
    const float* f2b     = (const float*)d_in[20];
    const float* ipw     = (const float*)d_in[21];
    const float* ipb     = (const float*)d_in[22];
    const float* alpha   = (const float*)d_in[23];
    float* out = (float*)d_out;

    // --- workspace arena (floats), total ~37.4M floats ~150 MB ---
    float* W = (float*)d_ws;
    size_t o = 0;
    auto alloc = [&](size_t n) { float* p = W + o; o += n; return p; };
    float* Z     = alloc(BNH);
    float* CTX   = alloc(BNH);
    float* FN    = alloc(BNH);
    float* PROJ0 = alloc(BNH);
    float* R     = alloc(12417024);          // shared transient region
    float* TOK   = alloc((size_t)96 * Hc);
    float* QKVWG = alloc((size_t)96 * 1536);
    float* MASS  = alloc(96); float* DOT = alloc(96); float* NRMP = alloc(96);
    float* NRMC  = alloc(32); float* SW  = alloc(96); float* INVM = alloc(96);
    float* MSUM  = alloc(32);
    float* KLACC = alloc(1);

    // R overlays (lifetimes are disjoint, same-stream ordering serializes):
    float* PEc  = R;                          // 4,657,152
    float* H1c  = R + PEC_SZ;                 // 4,657,152
    float* ZFc  = R + 2 * PEC_SZ;             // 1,552,384  (ends 10,866,688)
    float* QKVc = R;                          // 4,657,152
    float* HIDc = R;                          // 6,209,536
    float* FFNOUT = R + HIDC_SZ;              // 6,207,488  (ends 12,417,024)

    const size_t OUT_DISTILL = 2 * BNH;
    const size_t OUT_AW = 2 * BNH + 1;

    hipMemsetAsync(KLACC, 0, sizeof(float), stream);

    int eb = 256;
    int gBNH = (int)((BNH + eb - 1) / eb);
    int gCHK = (int)((CHUNK_NH + eb - 1) / eb);

    for (int s = 0; s < 2; s++) {
        // pre-LN
        ln_k<<<ROWS_BN, 256, 0, stream>>>(x[s], ln_g + s * Hc, ln_b + s * Hc, Z);
        // weight-gen stats + softmax weights
        wg_stats_k<<<Bc * (Pc + 1), 256, 0, stream>>>(pri[s], conn[s], MASS, DOT, NRMP, NRMC);
        wg_sw_k<<<1, 64, 0, stream>>>(MASS, DOT, NRMP, NRMC, SW, INVM);

        // ---- weight-gen pipeline, chunked over batches ----
        for (int c = 0; c < NCHUNK; c++) {
            const float* pric = pri[s] + (size_t)c * ROWS_WG * Nc;
            // zf_c = z_rows @ f1w[512:]
            launch_gemm<0>(Z + (size_t)c * ROWS_CHUNK * Hc, f1w + (size_t)Hc * Hc, ZFc,
                           ROWS_CHUNK, Hc, Hc, nullptr, nullptr, 0, nullptr, 0, 0, stream);
            // pe_c = (pri/mass)@pw + pb
            launch_gemm<4>(pric, pw, PEc, ROWS_WG, Hc, Nc, pb, INVM + c * CB * Pc, Nc,
                           nullptr, 0, 0, stream);
            // fused_nh rows for this chunk
            fused_nh_k<<<gCHK, eb, 0, stream>>>(PEc, SW + c * CB * Pc, FN + (size_t)c * CHUNK_NH, CHUNK_NH);
            // h1_c = gelu(pe_c @ f1w[:512] + zf_c + f1b)
            launch_gemm<3>(PEc, f1w, H1c, ROWS_WG, Hc, Hc, f1b, nullptr, 0, ZFc, Pc, Nc, stream);
            // f2_c = h1_c @ f2w + f2b  (overwrite pe_c)
            launch_gemm<1>(H1c, f2w, PEc, ROWS_WG, Hc, Hc, f2b, nullptr, 0, nullptr, 0, 0, stream);
            // tokens for this chunk
            tokens_k<<<CB * Pc, 512, 0, stream>>>(PEc, TOK + (size_t)c * CB * Pc * Hc);
        }
        // in-proj + tiny MHA -> aw (output) + msum
        launch_gemm<1>(TOK, ipw, QKVWG, Bc * Pc, 3 * Hc, Hc, ipb, nullptr, 0, nullptr, 0, 0, stream);
        wg_attn_k<<<Bc, 64, 0, stream>>>(QKVWG, out + OUT_AW + (size_t)s * (Bc * Pc), MSUM);

        // ---- main attention, chunked over batches (QKV chunk reuses R) ----
        for (int c = 0; c < NCHUNK; c++) {
            launch_gemm<0>(Z + (size_t)c * ROWS_CHUNK * Hc, wqkv[s], QKVc,
                           ROWS_CHUNK, 3 * Hc, Hc, nullptr, nullptr, 0, nullptr, 0, 0, stream);
            attn_k<<<dim3(Nc, NHc, CB), 256, 0, stream>>>(QKVc, conn[s], MSUM, alpha, c * CB, CTX);
        }
        // attn_out = x + ctx + fused_nh (in-place in CTX)
        add3_k<<<gBNH, eb, 0, stream>>>(x[s], CTX, FN, BNH);

        // ---- FFN, chunked rows ----
        ln_k<<<ROWS_BN, 256, 0, stream>>>(CTX, ln_g + (2 + s) * Hc, ln_b + (2 + s) * Hc, Z);
        for (int c = 0; c < NCHUNK; c++) {
            launch_gemm<2>(Z + (size_t)c * ROWS_CHUNK * Hc, ffn_w1 + (size_t)s * Hc * 4 * Hc, HIDc,
                           ROWS_CHUNK, 4 * Hc, Hc, ffn_b1 + (size_t)s * 4 * Hc,
                           nullptr, 0, nullptr, 0, 0, stream);
            launch_gemm<1>(HIDc, ffn_w2 + (size_t)s * 4 * Hc * Hc, FFNOUT + (size_t)c * ROWS_CHUNK * Hc,
                           ROWS_CHUNK, Hc, 4 * Hc, ffn_b2 + (size_t)s * Hc,
                           nullptr, 0, nullptr, 0, 0, stream);
        }
        // outputs (+ KL for stream 1)
        if (s == 0) {
            final_k<<<gBNH, eb, 0, stream>>>(CTX, FFNOUT, dw, out, PROJ0, BNH);
        } else {
            final_kl_k<<<ROWS_BN, 256, 0, stream>>>(CTX, FFNOUT, dw, PROJ0, out + BNH, KLACC);
        }
    }
    kl_final_k<<<1, 1, 0, stream>>>(KLACC, out + OUT_DISTILL);
}